// Round 1
// baseline (314.912 us; speedup 1.0000x reference)
//
#include <hip/hip_runtime.h>
#include <math.h>

#define B_TOT 8192
#define L_HIST 512
#define HF 64
#define LPE 8          // lanes per element
#define NPL 4          // neurons per lane (32/LPE)

__device__ __forceinline__ float fast_tanh(float x) {
    // tanh(x) = 1 - 2/(exp(2x)+1); exp(2x) = exp2(2*log2(e)*x)
    float e = __builtin_amdgcn_exp2f(x * 2.88539008177792681472f);
    float r = __builtin_amdgcn_rcpf(e + 1.0f);
    return fmaf(-2.0f, r, 1.0f);
}

__global__ __launch_bounds__(256) void kf_kernel(
    const float* __restrict__ v_hist,
    const float* __restrict__ dt_hist,
    const float* __restrict__ x_obs,
    const float* __restrict__ v_fut,
    const float* __restrict__ dt_fut,
    const float* __restrict__ p_log_tau_n,
    const float* __restrict__ p_log_q_n,
    const float* __restrict__ p_log_R_white,
    const float* __restrict__ p_log_P0_nn,
    const float* __restrict__ p_log_p0_xx,
    const float* __restrict__ p_log_p0_uu,
    const float* __restrict__ p_alpha,
    const float* __restrict__ p_c,
    const float* __restrict__ p_kappa,
    const float* __restrict__ p_vc,
    const float* __restrict__ p_qx,
    const float* __restrict__ p_qu,
    const float* __restrict__ p_q_scale,
    const float* __restrict__ W1,
    const float* __restrict__ b1,
    const float* __restrict__ W2,
    const float* __restrict__ b2,
    float* __restrict__ out)
{
    int tid = blockIdx.x * blockDim.x + threadIdx.x;
    int elem = tid >> 3;     // element index
    int lr = tid & 7;        // lane-within-group
    if (elem >= B_TOT) return;

    // one-time scalar setup
    float tau_n = expf(p_log_tau_n[0]);
    float q_n   = expf(p_log_q_n[0]);
    float R_w   = expf(p_log_R_white[0]);
    float P0nn  = expf(p_log_P0_nn[0]);
    float p0xx  = expf(p_log_p0_xx[0]);
    float p0uu  = expf(p_log_p0_uu[0]);
    float alpha = p_alpha[0], c = p_c[0], kappa = p_kappa[0], vc = p_vc[0];
    float qx = p_qx[0], qu = p_qu[0], qs = p_q_scale[0];
    const float LOG2E = 1.44269504088896340736f;
    float nal = -alpha * LOG2E;       // rho = exp2(nal*dt)
    float nph = -LOG2E / tau_n;       // phi = exp2(nph*dt)
    float vc2 = vc * vc;
    float qxs = qs * qx, qus = qs * qu;

    // per-lane slice of MLP weights: neurons [lr*NPL, lr*NPL+NPL)
    int j0 = lr * NPL;
    float w1u[NPL], w1v[NPL], w1d[NPL], bb[NPL], w2[NPL];
    #pragma unroll
    for (int j = 0; j < NPL; ++j) {
        w1u[j] = W1[j0 + j];          // W1[0][j]
        w1v[j] = W1[32 + j0 + j];     // W1[1][j]
        w1d[j] = W1[64 + j0 + j];     // W1[2][j]
        bb[j]  = b1[j0 + j];
        w2[j]  = W2[j0 + j];
    }
    float b2v = b2[0];

    const float* vh = v_hist + (size_t)elem * L_HIST;
    const float* dh = dt_hist + (size_t)elem * L_HIST;
    const float* oh = x_obs  + (size_t)elem * L_HIST;

    // state
    float x = oh[0], u = 0.f, n = 0.f;
    float p00 = p0xx, p11 = p0uu, p22 = P0nn;
    float p01 = 0.f, p02 = 0.f, p12 = 0.f;

    float v_prev = vh[0];   // ensures dv=0 at k=1

    for (int k = 1; k < L_HIST; ++k) {
        float dt  = fmaxf(dh[k], 1e-6f);
        float v_c = vh[k - 1];
        float dv  = v_c - v_prev;
        float obs = oh[k];
        v_prev = v_c;

        // ---- closure MLP (split across 8 lanes) ----
        float clp = 0.f;
        #pragma unroll
        for (int j = 0; j < NPL; ++j) {
            float t = fmaf(u, w1u[j], fmaf(v_c, w1v[j], fmaf(dv, w1d[j], bb[j])));
            clp = fmaf(fast_tanh(t), w2[j], clp);
        }
        clp += __shfl_xor(clp, 1);
        clp += __shfl_xor(clp, 2);
        clp += __shfl_xor(clp, 4);
        float cl = clp + b2v;

        // ---- predict ----
        float rho = __builtin_amdgcn_exp2f(nal * dt);
        float phi = __builtin_amdgcn_exp2f(nph * dt);
        float g = fmaxf(fmaf(v_c, v_c, -vc2), 0.f);
        float a = -kappa * dt;
        float x_p = fmaf(u, dt, x);
        float u_p = fmaf(rho, u, fmaf(a, x, fmaf(c, g, cl) * dt));
        float n_p = phi * n;
        // P_pred = F P F^T + Qd (F sparse, P symmetric: 6 entries)
        float t0 = fmaf(dt, p01, p00);
        float t1 = fmaf(dt, p11, p01);
        float t2 = fmaf(dt, p12, p02);
        float np00 = fmaf(dt, t1, t0) + qxs * dt;
        float np01 = fmaf(a, t0, rho * t1);
        float np02 = phi * t2;
        float u0 = fmaf(a, p00, rho * p01);
        float u1 = fmaf(a, p01, rho * p11);
        float u2 = fmaf(a, p02, rho * p12);
        float np11 = fmaf(a, u0, rho * u1) + qus * dt;
        float np12 = phi * u2;
        float np22 = fmaf(phi * phi, p22, q_n);

        // ---- Kalman update (Joseph form) ----
        float innov = obs - x_p - n_p;
        float r0 = np00 + np02;       // (P_pred h)_i , h = (1,0,1)
        float r1 = np01 + np12;
        float r2 = np02 + np22;
        float S = r0 + r2 + R_w;
        float rS = __builtin_amdgcn_rcpf(S);
        float k0 = r0 * rS, k1 = r1 * rS, k2 = r2 * rS;
        x = fmaf(k0, innov, x_p);
        u = fmaf(k1, innov, u_p);
        n = fmaf(k2, innov, n_p);
        // A = (I - K h^T) P_pred = P_pred - K r^T
        float A00 = fmaf(-k0, r0, np00);
        float A01 = fmaf(-k0, r1, np01);
        float A02 = fmaf(-k0, r2, np02);
        float A10 = fmaf(-k1, r0, np01);
        float A11 = fmaf(-k1, r1, np11);
        float A12 = fmaf(-k1, r2, np12);
        float A20 = fmaf(-k2, r0, np02);
        float A22 = fmaf(-k2, r2, np22);
        // P_new_ij = A_ij - (A h)_i k_j + Rw k_i k_j = A_ij + k_j*(Rw k_i - (Ah)_i)
        float m0 = fmaf(R_w, k0, -(A00 + A02));
        float m1 = fmaf(R_w, k1, -(A10 + A12));
        float m2 = fmaf(R_w, k2, -(A20 + A22));
        p00 = fmaf(k0, m0, A00);
        p01 = fmaf(k1, m0, A01);
        p02 = fmaf(k2, m0, A02);
        p11 = fmaf(k1, m1, A11);
        p12 = fmaf(k2, m1, A12);
        p22 = fmaf(k2, m2, A22);
    }

    // ---- forecast (predict only) ----
    const float* vf = v_fut + (size_t)elem * HF;
    const float* df = dt_fut + (size_t)elem * HF;
    float* ys  = out + (size_t)elem * HF;
    float* yvs = out + (size_t)B_TOT * HF + (size_t)elem * HF;

    v_prev = vh[L_HIST - 1];
    for (int j = 0; j < HF; ++j) {
        float dt  = fmaxf(df[j], 1e-6f);
        float v_c = vf[j];
        float dv  = v_c - v_prev;
        v_prev = v_c;

        float clp = 0.f;
        #pragma unroll
        for (int jj = 0; jj < NPL; ++jj) {
            float t = fmaf(u, w1u[jj], fmaf(v_c, w1v[jj], fmaf(dv, w1d[jj], bb[jj])));
            clp = fmaf(fast_tanh(t), w2[jj], clp);
        }
        clp += __shfl_xor(clp, 1);
        clp += __shfl_xor(clp, 2);
        clp += __shfl_xor(clp, 4);
        float cl = clp + b2v;

        float rho = __builtin_amdgcn_exp2f(nal * dt);
        float phi = __builtin_amdgcn_exp2f(nph * dt);
        float g = fmaxf(fmaf(v_c, v_c, -vc2), 0.f);
        float a = -kappa * dt;
        float x_p = fmaf(u, dt, x);
        float u_p = fmaf(rho, u, fmaf(a, x, fmaf(c, g, cl) * dt));
        float n_p = phi * n;
        float t0 = fmaf(dt, p01, p00);
        float t1 = fmaf(dt, p11, p01);
        float t2 = fmaf(dt, p12, p02);
        float np00 = fmaf(dt, t1, t0) + qxs * dt;
        float np01 = fmaf(a, t0, rho * t1);
        float np02 = phi * t2;
        float u0 = fmaf(a, p00, rho * p01);
        float u1 = fmaf(a, p01, rho * p11);
        float u2 = fmaf(a, p02, rho * p12);
        float np11 = fmaf(a, u0, rho * u1) + qus * dt;
        float np12 = phi * u2;
        float np22 = fmaf(phi * phi, p22, q_n);
        x = x_p; u = u_p; n = n_p;
        p00 = np00; p01 = np01; p02 = np02;
        p11 = np11; p12 = np12; p22 = np22;

        if (lr == 0) {
            ys[j]  = x + n;
            yvs[j] = p00 + 2.f * p02 + p22 + R_w;
        }
    }
    if (lr == 0) {
        out[(size_t)2 * B_TOT * HF + elem] = u;   // s[:,1:2]
    }
}

extern "C" void kernel_launch(void* const* d_in, const int* in_sizes, int n_in,
                              void* d_out, int out_size, void* d_ws, size_t ws_size,
                              hipStream_t stream) {
    const float* v_hist  = (const float*)d_in[0];
    const float* dt_hist = (const float*)d_in[1];
    const float* x_obs   = (const float*)d_in[2];
    const float* v_fut   = (const float*)d_in[3];
    const float* dt_fut  = (const float*)d_in[4];
    const float* log_tau_n   = (const float*)d_in[5];
    const float* log_q_n     = (const float*)d_in[6];
    const float* log_R_white = (const float*)d_in[7];
    const float* log_P0_nn   = (const float*)d_in[8];
    const float* log_p0_xx   = (const float*)d_in[9];
    const float* log_p0_uu   = (const float*)d_in[10];
    const float* alpha   = (const float*)d_in[11];
    const float* c       = (const float*)d_in[12];
    const float* kappa   = (const float*)d_in[13];
    const float* vc      = (const float*)d_in[14];
    const float* qx      = (const float*)d_in[15];
    const float* qu      = (const float*)d_in[16];
    const float* q_scale = (const float*)d_in[17];
    const float* W1 = (const float*)d_in[18];
    const float* b1 = (const float*)d_in[19];
    const float* W2 = (const float*)d_in[20];
    const float* b2 = (const float*)d_in[21];
    float* out = (float*)d_out;

    int threads = B_TOT * LPE;           // 65536
    dim3 block(256);
    dim3 grid(threads / 256);            // 256 blocks
    kf_kernel<<<grid, block, 0, stream>>>(
        v_hist, dt_hist, x_obs, v_fut, dt_fut,
        log_tau_n, log_q_n, log_R_white, log_P0_nn, log_p0_xx, log_p0_uu,
        alpha, c, kappa, vc, qx, qu, q_scale,
        W1, b1, W2, b2, out);
}

// Round 2
// 132.853 us; speedup vs baseline: 2.3704x; 2.3704x over previous
//
#include <hip/hip_runtime.h>
#include <math.h>

#define B_TOT 8192
#define L_HIST 512
#define HF 64

struct Consts {
    float nal, nph, kappa, c, vc2, qxs, qus, qn, Rw;
};
struct Wgt {   // per-lane slice: 4 neurons. u/v/d/b pre-scaled by 2*log2(e); n = -2*W2
    float u0,u1,u2,u3;
    float v0,v1,v2,v3;
    float d0,d1,d2,d3;
    float b0,b1,b2,b3;
    float n0,n1,n2,n3;
};
struct KS {
    float x,u,n,p00,p01,p02,p11,p12,p22;
};

// DPP-based 8-lane group sum: xor1, xor2 (quad_perm), then xor4 via
// row_half_mirror (lane i <-> i^7; valid because quads are uniform by then).
template<int CTRL>
__device__ __forceinline__ float dpp_add(float x) {
    int y = __builtin_amdgcn_update_dpp(__float_as_int(x), __float_as_int(x),
                                        CTRL, 0xF, 0xF, false);
    return x + __int_as_float(y);
}
__device__ __forceinline__ float gsum8(float x) {
    x = dpp_add<0xB1>(x);   // quad_perm [1,0,3,2]  = xor 1
    x = dpp_add<0x4E>(x);   // quad_perm [2,3,0,1]  = xor 2
    x = dpp_add<0x141>(x);  // row_half_mirror      = xor 7 ≡ xor 4 here
    return x;
}

template<bool UPD>
__device__ __forceinline__ void kstep(const Consts& C, const Wgt& w, float w2b,
                                      float dtraw, float v_c, float dv, float obs,
                                      KS& s)
{
    float dt  = fmaxf(dtraw, 1e-6f);
    float rho = __builtin_amdgcn_exp2f(C.nal * dt);
    float phi = __builtin_amdgcn_exp2f(C.nph * dt);
    float a   = -C.kappa * dt;
    float g    = fmaxf(fmaf(v_c, v_c, -C.vc2), 0.f);
    float cgdt = (C.c * g) * dt;

    // ---- MLP closure (4 neurons/lane, 8 lanes/element) ----
    // tanh(t) = 1 - 2*rcp(exp2(t*2log2e)+1); the 2log2e is folded into weights,
    // the (1, -2*w2) folding is in w2b / w.n*.
    float q0 = fmaf(v_c, w.v0, fmaf(dv, w.d0, w.b0));
    float q1 = fmaf(v_c, w.v1, fmaf(dv, w.d1, w.b1));
    float q2 = fmaf(v_c, w.v2, fmaf(dv, w.d2, w.b2));
    float q3 = fmaf(v_c, w.v3, fmaf(dv, w.d3, w.b3));
    float t0 = fmaf(s.u, w.u0, q0);
    float t1 = fmaf(s.u, w.u1, q1);
    float t2 = fmaf(s.u, w.u2, q2);
    float t3 = fmaf(s.u, w.u3, q3);
    float r0 = __builtin_amdgcn_rcpf(__builtin_amdgcn_exp2f(t0) + 1.f);
    float r1 = __builtin_amdgcn_rcpf(__builtin_amdgcn_exp2f(t1) + 1.f);
    float r2 = __builtin_amdgcn_rcpf(__builtin_amdgcn_exp2f(t2) + 1.f);
    float r3 = __builtin_amdgcn_rcpf(__builtin_amdgcn_exp2f(t3) + 1.f);
    float s01 = fmaf(w.n0, r0, w.n1 * r1);
    float s23 = fmaf(w.n2, r2, w.n3 * r3);
    float cl  = gsum8(s01 + s23) + w2b;

    // ---- predict ----
    float x_p = fmaf(s.u, dt, s.x);
    float u_p = fmaf(rho, s.u, fmaf(a, s.x, fmaf(cl, dt, cgdt)));
    float n_p = phi * s.n;

    float t0c = fmaf(dt, s.p01, s.p00);
    float t1c = fmaf(dt, s.p11, s.p01);
    float t2c = fmaf(dt, s.p12, s.p02);
    float np00 = fmaf(dt, t1c, t0c) + C.qxs * dt;
    float np01 = fmaf(a, t0c, rho * t1c);
    float np02 = phi * t2c;
    float u0c = fmaf(a, s.p00, rho * s.p01);
    float u1c = fmaf(a, s.p01, rho * s.p11);
    float u2c = fmaf(a, s.p02, rho * s.p12);
    float np11 = fmaf(a, u0c, rho * u1c) + C.qus * dt;
    float np12 = phi * u2c;
    float np22 = fmaf(phi * phi, s.p22, C.qn);

    if (UPD) {
        float innov = obs - x_p - n_p;
        float r0k = np00 + np02;
        float r1k = np01 + np12;
        float r2k = np02 + np22;
        float S  = r0k + r2k + C.Rw;
        float rS = __builtin_amdgcn_rcpf(S);
        float k0 = r0k * rS, k1 = r1k * rS, k2 = r2k * rS;
        s.x = fmaf(k0, innov, x_p);
        s.u = fmaf(k1, innov, u_p);
        s.n = fmaf(k2, innov, n_p);
        float A00 = fmaf(-k0, r0k, np00);
        float A01 = fmaf(-k0, r1k, np01);
        float A02 = fmaf(-k0, r2k, np02);
        float A10 = fmaf(-k1, r0k, np01);
        float A11 = fmaf(-k1, r1k, np11);
        float A12 = fmaf(-k1, r2k, np12);
        float A20 = fmaf(-k2, r0k, np02);
        float A22 = fmaf(-k2, r2k, np22);
        float m0 = fmaf(C.Rw, k0, -(A00 + A02));
        float m1 = fmaf(C.Rw, k1, -(A10 + A12));
        float m2 = fmaf(C.Rw, k2, -(A20 + A22));
        s.p00 = fmaf(k0, m0, A00);
        s.p01 = fmaf(k1, m0, A01);
        s.p02 = fmaf(k2, m0, A02);
        s.p11 = fmaf(k1, m1, A11);
        s.p12 = fmaf(k2, m1, A12);
        s.p22 = fmaf(k2, m2, A22);
    } else {
        s.x = x_p; s.u = u_p; s.n = n_p;
        s.p00 = np00; s.p01 = np01; s.p02 = np02;
        s.p11 = np11; s.p12 = np12; s.p22 = np22;
    }
}

__device__ __forceinline__ void fc_out(int lr, float* __restrict__ ys,
                                       float* __restrict__ yvs, int j,
                                       const KS& s, float Rw) {
    if (lr == 0) {
        ys[j]  = s.x + s.n;
        yvs[j] = s.p00 + 2.f * s.p02 + s.p22 + Rw;
    }
}

__global__ __launch_bounds__(256) void kf_kernel(
    const float* __restrict__ v_hist,
    const float* __restrict__ dt_hist,
    const float* __restrict__ x_obs,
    const float* __restrict__ v_fut,
    const float* __restrict__ dt_fut,
    const float* __restrict__ p_log_tau_n,
    const float* __restrict__ p_log_q_n,
    const float* __restrict__ p_log_R_white,
    const float* __restrict__ p_log_P0_nn,
    const float* __restrict__ p_log_p0_xx,
    const float* __restrict__ p_log_p0_uu,
    const float* __restrict__ p_alpha,
    const float* __restrict__ p_c,
    const float* __restrict__ p_kappa,
    const float* __restrict__ p_vc,
    const float* __restrict__ p_qx,
    const float* __restrict__ p_qu,
    const float* __restrict__ p_q_scale,
    const float* __restrict__ W1,
    const float* __restrict__ b1,
    const float* __restrict__ W2,
    const float* __restrict__ b2,
    float* __restrict__ out)
{
    int tid  = blockIdx.x * blockDim.x + threadIdx.x;
    int elem = tid >> 3;
    int lr   = tid & 7;
    if (elem >= B_TOT) return;

    const float LOG2E = 1.44269504088896340736f;
    const float K2    = 2.88539008177792681472f;   // 2*log2(e)

    Consts C;
    C.nal   = -p_alpha[0] * LOG2E;
    C.nph   = -LOG2E * expf(-p_log_tau_n[0]);      // -log2e / tau_n
    C.kappa = p_kappa[0];
    C.c     = p_c[0];
    { float vc = p_vc[0]; C.vc2 = vc * vc; }
    { float qs = p_q_scale[0]; C.qxs = qs * p_qx[0]; C.qus = qs * p_qu[0]; }
    C.qn = expf(p_log_q_n[0]);
    C.Rw = expf(p_log_R_white[0]);
    float p0xx = expf(p_log_p0_xx[0]);
    float p0uu = expf(p_log_p0_uu[0]);
    float P0nn = expf(p_log_P0_nn[0]);

    int j0 = lr * 4;
    Wgt w;
    w.u0 = W1[j0+0]*K2; w.u1 = W1[j0+1]*K2; w.u2 = W1[j0+2]*K2; w.u3 = W1[j0+3]*K2;
    w.v0 = W1[32+j0+0]*K2; w.v1 = W1[32+j0+1]*K2; w.v2 = W1[32+j0+2]*K2; w.v3 = W1[32+j0+3]*K2;
    w.d0 = W1[64+j0+0]*K2; w.d1 = W1[64+j0+1]*K2; w.d2 = W1[64+j0+2]*K2; w.d3 = W1[64+j0+3]*K2;
    w.b0 = b1[j0+0]*K2; w.b1 = b1[j0+1]*K2; w.b2 = b1[j0+2]*K2; w.b3 = b1[j0+3]*K2;
    float wa = W2[j0+0], wb = W2[j0+1], wc = W2[j0+2], wd = W2[j0+3];
    w.n0 = -2.f*wa; w.n1 = -2.f*wb; w.n2 = -2.f*wc; w.n3 = -2.f*wd;
    float w2b = gsum8(wa + wb + wc + wd) + b2[0];   // sum(W2) + b2 (tanh->1-2r fold)

    const float* vh = v_hist  + (size_t)elem * L_HIST;
    const float* dh = dt_hist + (size_t)elem * L_HIST;
    const float* oh = x_obs   + (size_t)elem * L_HIST;

    // chunk 0 (idx 0..3) + prefetch chunk 1
    float4 v0c = *(const float4*)(vh);
    float4 d0c = *(const float4*)(dh);
    float4 o0c = *(const float4*)(oh);
    float4 vC  = *(const float4*)(vh + 4);
    float4 dC  = *(const float4*)(dh + 4);
    float4 oC  = *(const float4*)(oh + 4);

    KS s;
    s.x = o0c.x; s.u = 0.f; s.n = 0.f;
    s.p00 = p0xx; s.p11 = p0uu; s.p22 = P0nn;
    s.p01 = 0.f; s.p02 = 0.f; s.p12 = 0.f;

    // steps 1..3
    kstep<true>(C, w, w2b, d0c.y, v0c.x, 0.f,         o0c.y, s);
    kstep<true>(C, w, w2b, d0c.z, v0c.y, v0c.y-v0c.x, o0c.z, s);
    kstep<true>(C, w, w2b, d0c.w, v0c.z, v0c.z-v0c.y, o0c.w, s);
    float vm2 = v0c.z, vm1 = v0c.w;

    // chunks 1..126 (steps 4..507), one-chunk-ahead prefetch
    for (int cch = 1; cch < 127; ++cch) {
        int kb = cch * 4;
        float4 vN = *(const float4*)(vh + kb + 4);
        float4 dN = *(const float4*)(dh + kb + 4);
        float4 oN = *(const float4*)(oh + kb + 4);
        kstep<true>(C, w, w2b, dC.x, vm1,  vm1 - vm2,  oC.x, s);
        kstep<true>(C, w, w2b, dC.y, vC.x, vC.x - vm1, oC.y, s);
        kstep<true>(C, w, w2b, dC.z, vC.y, vC.y - vC.x, oC.z, s);
        kstep<true>(C, w, w2b, dC.w, vC.z, vC.z - vC.y, oC.w, s);
        vm2 = vC.z; vm1 = vC.w;
        vC = vN; dC = dN; oC = oN;
    }

    // prefetch forecast chunk 0, then final filter chunk (steps 508..511)
    const float* vf = v_fut  + (size_t)elem * HF;
    const float* df = dt_fut + (size_t)elem * HF;
    float4 vFc = *(const float4*)(vf);
    float4 dFc = *(const float4*)(df);

    kstep<true>(C, w, w2b, dC.x, vm1,  vm1 - vm2,  oC.x, s);
    kstep<true>(C, w, w2b, dC.y, vC.x, vC.x - vm1, oC.y, s);
    kstep<true>(C, w, w2b, dC.z, vC.y, vC.y - vC.x, oC.z, s);
    kstep<true>(C, w, w2b, dC.w, vC.z, vC.z - vC.y, oC.w, s);
    float vprev = vC.w;   // vh[511]

    // ---- forecast: 16 chunks of 4 ----
    float* ys  = out + (size_t)elem * HF;
    float* yvs = out + (size_t)B_TOT * HF + (size_t)elem * HF;

    for (int f = 0; f < 15; ++f) {
        int jb = f * 4;
        float4 vN = *(const float4*)(vf + jb + 4);
        float4 dN = *(const float4*)(df + jb + 4);
        kstep<false>(C, w, w2b, dFc.x, vFc.x, vFc.x - vprev, 0.f, s);
        fc_out(lr, ys, yvs, jb + 0, s, C.Rw);
        kstep<false>(C, w, w2b, dFc.y, vFc.y, vFc.y - vFc.x, 0.f, s);
        fc_out(lr, ys, yvs, jb + 1, s, C.Rw);
        kstep<false>(C, w, w2b, dFc.z, vFc.z, vFc.z - vFc.y, 0.f, s);
        fc_out(lr, ys, yvs, jb + 2, s, C.Rw);
        kstep<false>(C, w, w2b, dFc.w, vFc.w, vFc.w - vFc.z, 0.f, s);
        fc_out(lr, ys, yvs, jb + 3, s, C.Rw);
        vprev = vFc.w;
        vFc = vN; dFc = dN;
    }
    // last chunk (steps 60..63)
    kstep<false>(C, w, w2b, dFc.x, vFc.x, vFc.x - vprev, 0.f, s);
    fc_out(lr, ys, yvs, 60, s, C.Rw);
    kstep<false>(C, w, w2b, dFc.y, vFc.y, vFc.y - vFc.x, 0.f, s);
    fc_out(lr, ys, yvs, 61, s, C.Rw);
    kstep<false>(C, w, w2b, dFc.z, vFc.z, vFc.z - vFc.y, 0.f, s);
    fc_out(lr, ys, yvs, 62, s, C.Rw);
    kstep<false>(C, w, w2b, dFc.w, vFc.w, vFc.w - vFc.z, 0.f, s);
    fc_out(lr, ys, yvs, 63, s, C.Rw);

    if (lr == 0) {
        out[(size_t)2 * B_TOT * HF + elem] = s.u;
    }
}

extern "C" void kernel_launch(void* const* d_in, const int* in_sizes, int n_in,
                              void* d_out, int out_size, void* d_ws, size_t ws_size,
                              hipStream_t stream) {
    const float* v_hist  = (const float*)d_in[0];
    const float* dt_hist = (const float*)d_in[1];
    const float* x_obs   = (const float*)d_in[2];
    const float* v_fut   = (const float*)d_in[3];
    const float* dt_fut  = (const float*)d_in[4];
    const float* log_tau_n   = (const float*)d_in[5];
    const float* log_q_n     = (const float*)d_in[6];
    const float* log_R_white = (const float*)d_in[7];
    const float* log_P0_nn   = (const float*)d_in[8];
    const float* log_p0_xx   = (const float*)d_in[9];
    const float* log_p0_uu   = (const float*)d_in[10];
    const float* alpha   = (const float*)d_in[11];
    const float* c       = (const float*)d_in[12];
    const float* kappa   = (const float*)d_in[13];
    const float* vc      = (const float*)d_in[14];
    const float* qx      = (const float*)d_in[15];
    const float* qu      = (const float*)d_in[16];
    const float* q_scale = (const float*)d_in[17];
    const float* W1 = (const float*)d_in[18];
    const float* b1 = (const float*)d_in[19];
    const float* W2 = (const float*)d_in[20];
    const float* b2 = (const float*)d_in[21];
    float* out = (float*)d_out;

    dim3 block(256);
    dim3 grid((B_TOT * 8) / 256);   // 65536 threads = 1024 waves = 1/SIMD
    kf_kernel<<<grid, block, 0, stream>>>(
        v_hist, dt_hist, x_obs, v_fut, dt_fut,
        log_tau_n, log_q_n, log_R_white, log_P0_nn, log_p0_xx, log_p0_uu,
        alpha, c, kappa, vc, qx, qu, q_scale,
        W1, b1, W2, b2, out);
}

// Round 3
// 129.860 us; speedup vs baseline: 2.4250x; 1.0230x over previous
//
#include <hip/hip_runtime.h>
#include <math.h>

#define B_TOT 8192
#define L_HIST 512
#define HF 64

typedef __attribute__((ext_vector_type(2))) float f2;

__device__ __forceinline__ f2 bc(float x) { f2 r; r.x = x; r.y = x; return r; }
__device__ __forceinline__ f2 fma2(f2 a, f2 b, f2 c) {
    return __builtin_elementwise_fma(a, b, c);
}

struct Consts {
    f2 expc;              // {-alpha, -1/tau_n}
    float kappa, c, vc2, qxs, qus, qn, Rw;
};
struct Wgt {              // per-lane 4 neurons as 2 packed pairs
    f2 wu0, wu1, wv0, wv1, wd0, wd1, wb0, wb1, wn0, wn1;
};
struct KS { float x, u, n, p00, p01, p02, p11, p12, p22; };

// DPP 8-lane group sum: xor1, xor2 (quad_perm), xor4 (row_half_mirror).
template<int CTRL>
__device__ __forceinline__ float dpp_add(float x) {
    int y = __builtin_amdgcn_update_dpp(__float_as_int(x), __float_as_int(x),
                                        CTRL, 0xF, 0xF, false);
    return x + __int_as_float(y);
}
__device__ __forceinline__ float gsum8(float x) {
    x = dpp_add<0xB1>(x);
    x = dpp_add<0x4E>(x);
    x = dpp_add<0x141>(x);
    return x;
}

// 4 neurons of tanh-MLP closure, packed 2x2; Pade-7/6 tanh, batched rcp.
__device__ __forceinline__ float mlp4(const Wgt& w, float u, float v, float dv) {
    f2 uu = bc(u), vv = bc(v), dd = bc(dv);
    f2 t0 = fma2(uu, w.wu0, fma2(vv, w.wv0, fma2(dd, w.wd0, w.wb0)));
    f2 t1 = fma2(uu, w.wu1, fma2(vv, w.wv1, fma2(dd, w.wd1, w.wb1)));
    t0 = __builtin_elementwise_min(__builtin_elementwise_max(t0, bc(-4.6f)), bc(4.6f));
    t1 = __builtin_elementwise_min(__builtin_elementwise_max(t1, bc(-4.6f)), bc(4.6f));
    f2 s0 = t0 * t0, s1 = t1 * t1;
    // numerator: t*(x6 + 378 x4 + 17325 x2 + 135135)
    f2 h0 = fma2(s0 + bc(378.f), s0, bc(17325.f));
    h0 = fma2(h0, s0, bc(135135.f));  h0 = h0 * t0;
    f2 h1 = fma2(s1 + bc(378.f), s1, bc(17325.f));
    h1 = fma2(h1, s1, bc(135135.f));  h1 = h1 * t1;
    // denominator: 28 x6 + 3150 x4 + 62370 x2 + 135135
    f2 d0 = fma2(bc(28.f), s0, bc(3150.f));
    d0 = fma2(d0, s0, bc(62370.f));   d0 = fma2(d0, s0, bc(135135.f));
    f2 d1 = fma2(bc(28.f), s1, bc(3150.f));
    d1 = fma2(d1, s1, bc(62370.f));   d1 = fma2(d1, s1, bc(135135.f));
    // batched reciprocal: one rcp inverts all four denominators
    float P1 = d0.x * d0.y, P2 = d1.x * d1.y;
    float rD = __builtin_amdgcn_rcpf(P1 * P2);
    float rA = rD * P2, rB = rD * P1;
    f2 i0; i0.x = rA * d0.y; i0.y = rA * d0.x;
    f2 i1; i1.x = rB * d1.y; i1.y = rB * d1.x;
    f2 acc = fma2(w.wn0, h0 * i0, w.wn1 * (h1 * i1));
    return acc.x + acc.y;
}

template<bool UPD>
__device__ __forceinline__ void kstep(const Consts& C, const Wgt& w, float b2v,
                                      float dtraw, float v_c, float dv, float obs,
                                      KS& s)
{
    float dt = fmaxf(dtraw, 1e-6f);
    // rho = exp(-alpha dt), phi = exp(-dt/tau): 4th-order Taylor, packed.
    // |z| <= 0.2 for dt in [0.01,0.1] -> err <= 2.7e-6.
    f2 z = C.expc * bc(dt);
    f2 e = fma2(fma2(fma2(fma2(z, bc(0.041666668f), bc(0.16666667f)),
                          z, bc(0.5f)), z, bc(1.0f)), z, bc(1.0f));
    float rho = e.x, phi = e.y;
    float a = -C.kappa * dt;
    float g = fmaxf(fmaf(v_c, v_c, -C.vc2), 0.f);
    float cgdt = (C.c * g) * dt;

    float cl = gsum8(mlp4(w, s.u, v_c, dv)) + b2v;

    // ---- predict ----
    float x_p = fmaf(s.u, dt, s.x);
    float u_p = fmaf(rho, s.u, fmaf(a, s.x, fmaf(cl, dt, cgdt)));
    float n_p = phi * s.n;

    float t0c = fmaf(dt, s.p01, s.p00);
    float t1c = fmaf(dt, s.p11, s.p01);
    float t2c = fmaf(dt, s.p12, s.p02);
    float np00 = fmaf(dt, t1c, t0c) + C.qxs * dt;
    float np01 = fmaf(a, t0c, rho * t1c);
    float np02 = phi * t2c;
    float u0c = fmaf(a, s.p00, rho * s.p01);
    float u1c = fmaf(a, s.p01, rho * s.p11);
    float u2c = fmaf(a, s.p02, rho * s.p12);
    float np11 = fmaf(a, u0c, rho * u1c) + C.qus * dt;
    float np12 = phi * u2c;
    float np22 = fmaf(phi * phi, s.p22, C.qn);

    if (UPD) {
        float innov = obs - x_p - n_p;
        float r0k = np00 + np02;
        float r1k = np01 + np12;
        float r2k = np02 + np22;
        float S  = r0k + r2k + C.Rw;
        float rS = __builtin_amdgcn_rcpf(S);
        float k0 = r0k * rS, k1 = r1k * rS, k2 = r2k * rS;
        s.x = fmaf(k0, innov, x_p);
        s.u = fmaf(k1, innov, u_p);
        s.n = fmaf(k2, innov, n_p);
        // simple-form update (== Joseph for optimal K): P = P_pred - K r^T
        s.p00 = fmaf(-k0, r0k, np00);
        s.p01 = fmaf(-k0, r1k, np01);
        s.p02 = fmaf(-k0, r2k, np02);
        s.p11 = fmaf(-k1, r1k, np11);
        s.p12 = fmaf(-k1, r2k, np12);
        s.p22 = fmaf(-k2, r2k, np22);
    } else {
        s.x = x_p; s.u = u_p; s.n = n_p;
        s.p00 = np00; s.p01 = np01; s.p02 = np02;
        s.p11 = np11; s.p12 = np12; s.p22 = np22;
    }
}

__device__ __forceinline__ void fc_out(int lr, float* __restrict__ ys,
                                       float* __restrict__ yvs, int j,
                                       const KS& s, float Rw) {
    if (lr == 0) {
        ys[j]  = s.x + s.n;
        yvs[j] = s.p00 + 2.f * s.p02 + s.p22 + Rw;
    }
}

__global__ __launch_bounds__(256) void kf_kernel(
    const float* __restrict__ v_hist,
    const float* __restrict__ dt_hist,
    const float* __restrict__ x_obs,
    const float* __restrict__ v_fut,
    const float* __restrict__ dt_fut,
    const float* __restrict__ p_log_tau_n,
    const float* __restrict__ p_log_q_n,
    const float* __restrict__ p_log_R_white,
    const float* __restrict__ p_log_P0_nn,
    const float* __restrict__ p_log_p0_xx,
    const float* __restrict__ p_log_p0_uu,
    const float* __restrict__ p_alpha,
    const float* __restrict__ p_c,
    const float* __restrict__ p_kappa,
    const float* __restrict__ p_vc,
    const float* __restrict__ p_qx,
    const float* __restrict__ p_qu,
    const float* __restrict__ p_q_scale,
    const float* __restrict__ W1,
    const float* __restrict__ b1,
    const float* __restrict__ W2,
    const float* __restrict__ b2,
    float* __restrict__ out)
{
    int tid  = blockIdx.x * blockDim.x + threadIdx.x;
    int elem = tid >> 3;
    int lr   = tid & 7;
    if (elem >= B_TOT) return;

    Consts C;
    C.expc.x = -p_alpha[0];
    C.expc.y = -expf(-p_log_tau_n[0]);   // -1/tau_n
    C.kappa = p_kappa[0];
    C.c     = p_c[0];
    { float vc = p_vc[0]; C.vc2 = vc * vc; }
    { float qs = p_q_scale[0]; C.qxs = qs * p_qx[0]; C.qus = qs * p_qu[0]; }
    C.qn = expf(p_log_q_n[0]);
    C.Rw = expf(p_log_R_white[0]);
    float p0xx = expf(p_log_p0_xx[0]);
    float p0uu = expf(p_log_p0_uu[0]);
    float P0nn = expf(p_log_P0_nn[0]);

    int j0 = lr * 4;
    Wgt w;
    w.wu0.x = W1[j0+0];    w.wu0.y = W1[j0+1];
    w.wu1.x = W1[j0+2];    w.wu1.y = W1[j0+3];
    w.wv0.x = W1[32+j0+0]; w.wv0.y = W1[32+j0+1];
    w.wv1.x = W1[32+j0+2]; w.wv1.y = W1[32+j0+3];
    w.wd0.x = W1[64+j0+0]; w.wd0.y = W1[64+j0+1];
    w.wd1.x = W1[64+j0+2]; w.wd1.y = W1[64+j0+3];
    w.wb0.x = b1[j0+0];    w.wb0.y = b1[j0+1];
    w.wb1.x = b1[j0+2];    w.wb1.y = b1[j0+3];
    w.wn0.x = W2[j0+0];    w.wn0.y = W2[j0+1];
    w.wn1.x = W2[j0+2];    w.wn1.y = W2[j0+3];
    float b2v = b2[0];

    const float* vh = v_hist  + (size_t)elem * L_HIST;
    const float* dh = dt_hist + (size_t)elem * L_HIST;
    const float* oh = x_obs   + (size_t)elem * L_HIST;

    float4 v0c = *(const float4*)(vh);
    float4 d0c = *(const float4*)(dh);
    float4 o0c = *(const float4*)(oh);
    float4 vC  = *(const float4*)(vh + 4);
    float4 dC  = *(const float4*)(dh + 4);
    float4 oC  = *(const float4*)(oh + 4);

    KS s;
    s.x = o0c.x; s.u = 0.f; s.n = 0.f;
    s.p00 = p0xx; s.p11 = p0uu; s.p22 = P0nn;
    s.p01 = 0.f; s.p02 = 0.f; s.p12 = 0.f;

    kstep<true>(C, w, b2v, d0c.y, v0c.x, 0.f,           o0c.y, s);
    kstep<true>(C, w, b2v, d0c.z, v0c.y, v0c.y - v0c.x, o0c.z, s);
    kstep<true>(C, w, b2v, d0c.w, v0c.z, v0c.z - v0c.y, o0c.w, s);
    float vm2 = v0c.z, vm1 = v0c.w;

    for (int cch = 1; cch < 127; ++cch) {
        int kb = cch * 4;
        float4 vN = *(const float4*)(vh + kb + 4);
        float4 dN = *(const float4*)(dh + kb + 4);
        float4 oN = *(const float4*)(oh + kb + 4);
        kstep<true>(C, w, b2v, dC.x, vm1,  vm1 - vm2,   oC.x, s);
        kstep<true>(C, w, b2v, dC.y, vC.x, vC.x - vm1,  oC.y, s);
        kstep<true>(C, w, b2v, dC.z, vC.y, vC.y - vC.x, oC.z, s);
        kstep<true>(C, w, b2v, dC.w, vC.z, vC.z - vC.y, oC.w, s);
        vm2 = vC.z; vm1 = vC.w;
        vC = vN; dC = dN; oC = oN;
    }

    const float* vf = v_fut  + (size_t)elem * HF;
    const float* df = dt_fut + (size_t)elem * HF;
    float4 vFc = *(const float4*)(vf);
    float4 dFc = *(const float4*)(df);

    kstep<true>(C, w, b2v, dC.x, vm1,  vm1 - vm2,   oC.x, s);
    kstep<true>(C, w, b2v, dC.y, vC.x, vC.x - vm1,  oC.y, s);
    kstep<true>(C, w, b2v, dC.z, vC.y, vC.y - vC.x, oC.z, s);
    kstep<true>(C, w, b2v, dC.w, vC.z, vC.z - vC.y, oC.w, s);
    float vprev = vC.w;

    float* ys  = out + (size_t)elem * HF;
    float* yvs = out + (size_t)B_TOT * HF + (size_t)elem * HF;

    for (int f = 0; f < 15; ++f) {
        int jb = f * 4;
        float4 vN = *(const float4*)(vf + jb + 4);
        float4 dN = *(const float4*)(df + jb + 4);
        kstep<false>(C, w, b2v, dFc.x, vFc.x, vFc.x - vprev, 0.f, s);
        fc_out(lr, ys, yvs, jb + 0, s, C.Rw);
        kstep<false>(C, w, b2v, dFc.y, vFc.y, vFc.y - vFc.x, 0.f, s);
        fc_out(lr, ys, yvs, jb + 1, s, C.Rw);
        kstep<false>(C, w, b2v, dFc.z, vFc.z, vFc.z - vFc.y, 0.f, s);
        fc_out(lr, ys, yvs, jb + 2, s, C.Rw);
        kstep<false>(C, w, b2v, dFc.w, vFc.w, vFc.w - vFc.z, 0.f, s);
        fc_out(lr, ys, yvs, jb + 3, s, C.Rw);
        vprev = vFc.w;
        vFc = vN; dFc = dN;
    }
    kstep<false>(C, w, b2v, dFc.x, vFc.x, vFc.x - vprev, 0.f, s);
    fc_out(lr, ys, yvs, 60, s, C.Rw);
    kstep<false>(C, w, b2v, dFc.y, vFc.y, vFc.y - vFc.x, 0.f, s);
    fc_out(lr, ys, yvs, 61, s, C.Rw);
    kstep<false>(C, w, b2v, dFc.z, vFc.z, vFc.z - vFc.y, 0.f, s);
    fc_out(lr, ys, yvs, 62, s, C.Rw);
    kstep<false>(C, w, b2v, dFc.w, vFc.w, vFc.w - vFc.z, 0.f, s);
    fc_out(lr, ys, yvs, 63, s, C.Rw);

    if (lr == 0) {
        out[(size_t)2 * B_TOT * HF + elem] = s.u;
    }
}

extern "C" void kernel_launch(void* const* d_in, const int* in_sizes, int n_in,
                              void* d_out, int out_size, void* d_ws, size_t ws_size,
                              hipStream_t stream) {
    const float* v_hist  = (const float*)d_in[0];
    const float* dt_hist = (const float*)d_in[1];
    const float* x_obs   = (const float*)d_in[2];
    const float* v_fut   = (const float*)d_in[3];
    const float* dt_fut  = (const float*)d_in[4];
    const float* log_tau_n   = (const float*)d_in[5];
    const float* log_q_n     = (const float*)d_in[6];
    const float* log_R_white = (const float*)d_in[7];
    const float* log_P0_nn   = (const float*)d_in[8];
    const float* log_p0_xx   = (const float*)d_in[9];
    const float* log_p0_uu   = (const float*)d_in[10];
    const float* alpha   = (const float*)d_in[11];
    const float* c       = (const float*)d_in[12];
    const float* kappa   = (const float*)d_in[13];
    const float* vc      = (const float*)d_in[14];
    const float* qx      = (const float*)d_in[15];
    const float* qu      = (const float*)d_in[16];
    const float* q_scale = (const float*)d_in[17];
    const float* W1 = (const float*)d_in[18];
    const float* b1 = (const float*)d_in[19];
    const float* W2 = (const float*)d_in[20];
    const float* b2 = (const float*)d_in[21];
    float* out = (float*)d_out;

    dim3 block(256);
    dim3 grid((B_TOT * 8) / 256);
    kf_kernel<<<grid, block, 0, stream>>>(
        v_hist, dt_hist, x_obs, v_fut, dt_fut,
        log_tau_n, log_q_n, log_R_white, log_P0_nn, log_p0_xx, log_p0_uu,
        alpha, c, kappa, vc, qx, qu, q_scale,
        W1, b1, W2, b2, out);
}